// Round 1
// baseline (403.715 us; speedup 1.0000x reference)
//
#include <hip/hip_runtime.h>

// RGATConv x2 (N=50000, E=800000, IN=HID=128, R=8) for MI355X/gfx950.
//
// Round-9: k_gemm_xt operand swap — A=Wb (W^T fragments), B=x fragments.
// C/D layout now gives each lane 4 CONSECUTIVE channels of one node, so xt
// is stored directly from the accumulator (uint2, 8B) with NO LDS transpose
// and NO barriers. The [sq|sk] GEMM (old k_sqk, a full re-read of x) fuses
// into the same kernel: Bqk reused unchanged as A operand, 4 extra MFMAs.
// Rest identical to round-8.

typedef unsigned short u16;
typedef __attribute__((ext_vector_type(8))) short short8;
typedef __attribute__((ext_vector_type(4))) float floatx4;
typedef __attribute__((ext_vector_type(4))) float float4v;
typedef __attribute__((ext_vector_type(4))) unsigned uint4v;

__device__ __forceinline__ u16 f2bf(float f) {
  union { float f; unsigned u; } v; v.f = f;
  unsigned r = v.u + 0x7FFFu + ((v.u >> 16) & 1u);  // RNE
  return (u16)(r >> 16);
}
__device__ __forceinline__ float bflo(unsigned v) {
  union { unsigned u; float f; } c; c.u = v << 16; return c.f;
}
__device__ __forceinline__ float bfhi(unsigned v) {
  union { unsigned u; float f; } c; c.u = v & 0xffff0000u; return c.f;
}

// ---- 1. pack stacked W into fragment order (per graph) ----------------------
// Layout: [(kkq*8 + nt)*64 + lane]*8 where element = W[k][c],
// c = nt*16 + (lane&15), k = kkq*32 + (lane>>4)*8 + j.
// Valid as B-fragment (col=c) AND as A-fragment of W^T (row=c).
__global__ void k_prep_wb(const float* __restrict__ W1, const float* __restrict__ W2,
                          u16* __restrict__ Wb, int KK) {
  int t = blockIdx.x * 256 + threadIdx.x;
  int lane = t & 63, nt = (t >> 6) & 7, kk = t >> 9;
  if (kk >= KK) return;
  const float* W = blockIdx.y ? W2 : W1;
  u16* out = Wb + (size_t)blockIdx.y * KK * 4096;
  int q = lane >> 4, m16 = lane & 15;
  int c = nt * 16 + m16;
  short8 v;
#pragma unroll
  for (int j = 0; j < 8; ++j) {
    int k = kk * 32 + q * 8 + j;
    v[j] = (short)f2bf(W[(size_t)k * 128 + c]);
  }
  *(short8*)(out + (size_t)t * 8) = v;
}

// ---- 2. Wq[g][r][d] = sum_c W[r][d][c]*q[c]; Wk likewise --------------------
__global__ void k_prep_wqk(const float* __restrict__ W1, const float* __restrict__ q1,
                           const float* __restrict__ k1, const float* __restrict__ W2,
                           const float* __restrict__ q2, const float* __restrict__ k2,
                           float* __restrict__ Wq, float* __restrict__ Wk, int RD) {
  int wid = (blockIdx.x * 256 + threadIdx.x) >> 6;
  int lane = threadIdx.x & 63;
  if (wid >= 2 * RD) return;
  int g = wid >= RD;
  const float* W = g ? W2 : W1;
  const float* qv = g ? q2 : q1;
  const float* kv = g ? k2 : k1;
  const float* row = W + (size_t)(wid - g * RD) * 128;
  float a0 = row[lane], a1 = row[lane + 64];
  float vq = a0 * qv[lane] + a1 * qv[lane + 64];
  float vk = a0 * kv[lane] + a1 * kv[lane + 64];
#pragma unroll
  for (int off = 32; off; off >>= 1) {
    vq += __shfl_xor(vq, off);
    vk += __shfl_xor(vk, off);
  }
  if (lane == 0) { Wq[wid] = vq; Wk[wid] = vk; }
}

// ---- 3. Bqk[g][kk][lane][j]: fragment of [Wq|Wk] (16 rows/cols) -------------
__global__ void k_prep_bqk(const float* __restrict__ Wq, const float* __restrict__ Wk,
                           u16* __restrict__ Bqk, int R) {
  int total = 2 * 4 * 64 * 8;
  for (int idx = threadIdx.x; idx < total; idx += 256) {
    int j = idx & 7, lane = (idx >> 3) & 63, kk = (idx >> 9) & 3, g = idx >> 11;
    int k = kk * 32 + ((lane >> 4) & 3) * 8 + j;
    int n = lane & 15;
    float v = (n < 8) ? Wq[(g * R + n) * 128 + k] : Wk[(g * R + (n & 7)) * 128 + k];
    Bqk[idx] = f2bf(v);
  }
}

// ---- 5a. bucket-level counts (LDS hist per block) ---------------------------
__global__ void __launch_bounds__(256) k_count(
    const int* __restrict__ d1, const int* __restrict__ d2,
    int* __restrict__ gcnt, int N, int E, int NB) {
  __shared__ int h[512];
  int tid = threadIdx.x;
  for (int i = tid; i < NB; i += 256) h[i] = 0;
  __syncthreads();
  int E2 = 2 * E;
  int e0 = blockIdx.x * 4096;
#pragma unroll
  for (int j = 0; j < 16; ++j) {
    int e = e0 + j * 256 + tid;
    if (e < E2) {
      int g = e >= E;
      int d = g ? d2[e - E] : d1[e];
      atomicAdd(&h[(g * N + d) >> 8], 1);
    }
  }
  __syncthreads();
  for (int i = tid; i < NB; i += 256)
    if (h[i]) atomicAdd(&gcnt[i], h[i]);
}

// ---- 5b. scan bucket totals -> bbase/bcur; offs[N2]=total -------------------
__global__ void k_bucket_scan(const int* __restrict__ gcnt, int* __restrict__ bbase,
                              int* __restrict__ bcur, int* __restrict__ offs,
                              int NB, int total, int N2) {
  __shared__ int sd[512];
  int tid = threadIdx.x;
  int v0 = (tid < NB) ? gcnt[tid] : 0;
  int v1 = (tid + 256 < NB) ? gcnt[tid + 256] : 0;
  sd[tid] = v0; sd[tid + 256] = v1;
  __syncthreads();
  for (int off = 1; off < 512; off <<= 1) {
    int t0 = (tid >= off) ? sd[tid - off] : 0;
    int t1 = (tid + 256 >= off) ? sd[tid + 256 - off] : 0;
    __syncthreads();
    sd[tid] += t0; sd[tid + 256] += t1;
    __syncthreads();
  }
  if (tid < NB) { int b = sd[tid] - v0; bbase[tid] = b; bcur[tid] = b; }
  if (tid + 256 < NB) { int b = sd[tid + 256] - v1; bbase[tid + 256] = b; bcur[tid + 256] = b; }
  if (tid == 0) { bbase[NB] = total; offs[N2] = total; }
}

// ---- 5c. bin edges into 256-node buckets (counting-sort per 4096-edge chunk)
__global__ void __launch_bounds__(256) k_bin(
    const int* __restrict__ ei1, const int* __restrict__ et1,
    const int* __restrict__ ei2, const int* __restrict__ et2,
    int* __restrict__ bcur, uint2* __restrict__ staged, int N, int E, int NB) {
  __shared__ int hist[512];
  __shared__ int basev[512];
  __shared__ int runstart[512];
  __shared__ unsigned sta[4096 * 2];  // 32 KB staging (dstg, srcet)
  int tid = threadIdx.x;
  int E2 = 2 * E;
  int e0 = blockIdx.x * 4096;
  int cnt2 = min(4096, E2 - e0);
  for (int i = tid; i < 512; i += 256) hist[i] = 0;
  __syncthreads();
  int dstg[16], srcet[16], rank[16];
#pragma unroll
  for (int j = 0; j < 16; ++j) {
    int e = e0 + j * 256 + tid;
    dstg[j] = -1;
    if (e < E2) {
      int g = e >= E;
      int el = e - (g ? E : 0);
      const int* ei = g ? ei2 : ei1;
      int s = ei[el], d = ei[E + el];
      int etv = (g ? et2 : et1)[el];
      dstg[j] = g * N + d;
      srcet[j] = (s << 3) | etv;
      rank[j] = atomicAdd(&hist[dstg[j] >> 8], 1);
    }
  }
  __syncthreads();
  basev[tid] = hist[tid];
  basev[tid + 256] = hist[tid + 256];
  __syncthreads();
  for (int off = 1; off < 512; off <<= 1) {
    int i0 = tid, i1 = tid + 256;
    int v0 = (i0 >= off) ? basev[i0 - off] : 0;
    int v1 = (i1 >= off) ? basev[i1 - off] : 0;
    __syncthreads();
    basev[i0] += v0; basev[i1] += v1;
    __syncthreads();
  }
  for (int i = tid; i < NB; i += 256)
    if (hist[i] > 0) runstart[i] = atomicAdd(&bcur[i], hist[i]);
  __syncthreads();
#pragma unroll
  for (int j = 0; j < 16; ++j)
    if (dstg[j] >= 0) {
      int b = dstg[j] >> 8;
      int slot = basev[b] - hist[b] + rank[j];
      sta[slot * 2] = (unsigned)dstg[j];
      sta[slot * 2 + 1] = (unsigned)srcet[j];
    }
  __syncthreads();
  for (int i = tid; i < cnt2; i += 256) {
    unsigned dg = sta[i * 2], se = sta[i * 2 + 1];
    int b = (int)(dg >> 8);
    int dest = runstart[b] + (i - (basev[b] - hist[b]));
    staged[dest] = make_uint2(dg, se);
  }
}

// ---- 5d. per-bucket: node-level offs + final sorted csr ---------------------
__global__ void __launch_bounds__(256) k_scatter2(
    const uint2* __restrict__ staged, const int* __restrict__ bbase,
    int* __restrict__ offs, int* __restrict__ csr, int N2) {
  __shared__ int hist[256];
  __shared__ int sd[256];
  __shared__ int cur[256];
  int b = blockIdx.x, tid = threadIdx.x;
  int nb0 = b << 8;
  int nnode = min(256, N2 - nb0);
  int s0 = bbase[b], s1 = bbase[b + 1];
  hist[tid] = 0;
  __syncthreads();
  for (int i = s0 + tid; i < s1; i += 256)
    atomicAdd(&hist[(int)staged[i].x - nb0], 1);
  __syncthreads();
  int v = hist[tid];
  sd[tid] = v; __syncthreads();
  for (int off = 1; off < 256; off <<= 1) {
    int t = (tid >= off) ? sd[tid - off] : 0;
    __syncthreads();
    sd[tid] += t;
    __syncthreads();
  }
  int ex = sd[tid] - v;  // exclusive scan
  if (tid < nnode) offs[nb0 + tid] = s0 + ex;
  cur[tid] = ex;
  __syncthreads();
  for (int i = s0 + tid; i < s1; i += 256) {
    uint2 en = staged[i];
    int node = (int)en.x - nb0;
    int sl = atomicAdd(&cur[node], 1);
    csr[s0 + sl] = (int)en.y;
  }
}

// ---- 6a. xt[r][n][c] = x_n @ W_r, fused [sq|sk] = x @ [Wq|Wk] ---------------
// A = Wb fragments (W^T: row index = out channel), B = x fragments (col =
// node). D[c][node]: lane holds col=node (lane&15), rows = channels
// nt*16 + q*4 + {0..3} (q = lane>>4) -> 4 consecutive channels -> direct
// 8B packed store. No LDS, no barriers.
__global__ void __launch_bounds__(256) k_gemm_xt(
    const float* __restrict__ x, const u16* __restrict__ Wb,
    const u16* __restrict__ Bqk, u16* __restrict__ xt,
    float* __restrict__ sq, float* __restrict__ sk,
    int N, int R, int node_base) {
  int wave = threadIdx.x >> 6, lane = threadIdx.x & 63;
  int m0 = blockIdx.x * 64 + wave * 16;
  int q = lane >> 4, m16 = lane & 15;
  int node = m0 + m16;
  int srow = (node < N) ? node : N - 1;
  // B fragments of x: col = node, k = kk*32 + q*8 + j, loaded ONCE
  short8 bfrag[4];
#pragma unroll
  for (int kk = 0; kk < 4; ++kk) {
    const float* ap = x + (size_t)srow * 128 + kk * 32 + q * 8;
    float4v f0 = *(const float4v*)ap;
    float4v f1 = *(const float4v*)(ap + 4);
    short8 a;
    a[0] = (short)f2bf(f0.x); a[1] = (short)f2bf(f0.y);
    a[2] = (short)f2bf(f0.z); a[3] = (short)f2bf(f0.w);
    a[4] = (short)f2bf(f1.x); a[5] = (short)f2bf(f1.y);
    a[6] = (short)f2bf(f1.z); a[7] = (short)f2bf(f1.w);
    bfrag[kk] = a;
  }
  // fused [sq|sk]: A = Bqk (row i: 0-7 -> Wq rows, 8-15 -> Wk rows).
  // Lane q=0: sq[node][0..3], q=1: sq[node][4..7], q=2: sk[0..3], q=3: sk[4..7]
  {
    floatx4 accq = (floatx4){0.f, 0.f, 0.f, 0.f};
#pragma unroll
    for (int kk = 0; kk < 4; ++kk) {
      short8 aq = *(const short8*)(Bqk + (size_t)kk * 512 + lane * 8);
      accq = __builtin_amdgcn_mfma_f32_16x16x32_bf16(aq, bfrag[kk], accq, 0, 0, 0);
    }
    if (node < N) {
      float* dst = (q < 2 ? sq : sk) + (size_t)(node_base + node) * 8 + (q & 1) * 4;
      *(float4v*)dst = (float4v){accq[0], accq[1], accq[2], accq[3]};
    }
  }
  for (int r = 0; r < R; ++r) {
    floatx4 acc[8];
#pragma unroll
    for (int nt = 0; nt < 8; ++nt) acc[nt] = (floatx4){0.f, 0.f, 0.f, 0.f};
#pragma unroll
    for (int kk = 0; kk < 4; ++kk) {
      const u16* wbp = Wb + ((size_t)((r * 4 + kk) * 8) * 64 + lane) * 8;
#pragma unroll
      for (int nt = 0; nt < 8; ++nt) {
        short8 a = *(const short8*)(wbp + nt * 512);
        acc[nt] = __builtin_amdgcn_mfma_f32_16x16x32_bf16(a, bfrag[kk], acc[nt], 0, 0, 0);
      }
    }
    if (node < N) {
      u16* rowp = xt + ((size_t)r * N + node) * 128 + q * 4;
#pragma unroll
      for (int nt = 0; nt < 8; ++nt) {
        union { u16 h[4]; uint2 u; } pk;
        pk.h[0] = f2bf(acc[nt][0]); pk.h[1] = f2bf(acc[nt][1]);
        pk.h[2] = f2bf(acc[nt][2]); pk.h[3] = f2bf(acc[nt][3]);
        *(uint2*)(rowp + nt * 16) = pk.u;
      }
    }
  }
}

// ---- 6b. per-dst softmax + gather: one wave per node ------------------------
__global__ void __launch_bounds__(256) k_aggregate(
    const int* __restrict__ csr, const int* __restrict__ offs,
    const float* __restrict__ sq, const float* __restrict__ sk,
    const u16* __restrict__ xt, const float* __restrict__ bias,
    float* __restrict__ out, int N, int node_base) {
  int nl = blockIdx.x * 4 + (threadIdx.x >> 6);
  int lane = threadIdx.x & 63;
  if (nl >= N) return;
  int node = node_base + nl;
  int start = offs[node], end = offs[node + 1];
  const float* sqn = sq + (size_t)node * 8;

  float al[8]; int pl[8];
  float m = -INFINITY;
  {
    int c = 0;
    for (int i = start + lane; i < end; i += 64, ++c) {
      int p = csr[i]; int s = p >> 3, e = p & 7;
      float a = sqn[e] + sk[(size_t)(node_base + s) * 8 + e];
      a = (a > 0.f) ? a : 0.2f * a;
      if (c < 8) { al[c] = a; pl[c] = p; }
      m = fmaxf(m, a);
    }
  }
#pragma unroll
  for (int off = 32; off; off >>= 1) m = fmaxf(m, __shfl_xor(m, off));

  float ssum = 0.f;
  {
    int c = 0;
    for (int i = start + lane; i < end; i += 64, ++c) {
      float a;
      if (c < 8) a = al[c];
      else {
        int p = csr[i]; int s = p >> 3, e = p & 7;
        a = sqn[e] + sk[(size_t)(node_base + s) * 8 + e];
        a = (a > 0.f) ? a : 0.2f * a;
      }
      ssum += __expf(a - m);
    }
  }
#pragma unroll
  for (int off = 32; off; off >>= 1) ssum += __shfl_xor(ssum, off);
  float inv = 1.f / (ssum + 1e-16f);

  float acc0 = 0.f, acc1 = 0.f;
  const char* xtb = (const char*)xt;
  int c = 0;
  for (int base = start; base < end; base += 64, ++c) {
    int cnt = min(64, end - base);
    float w = 0.f; int b = 0;
    {
      int i = base + lane;
      if (i < end) {
        int p; float a;
        if (c < 8) { p = pl[c]; a = al[c]; }
        else {
          p = csr[i]; int s = p >> 3, e = p & 7;
          a = sqn[e] + sk[(size_t)(node_base + s) * 8 + e];
          a = (a > 0.f) ? a : 0.2f * a;
        }
        w = __expf(a - m) * inv;
        b = ((p & 7) * N + (p >> 3)) << 8;  // xt row base in BYTES
      }
    }
    int j = 0;
    for (; j + 3 < cnt; j += 4) {
      float w0 = __shfl(w, j), w1 = __shfl(w, j + 1),
            w2 = __shfl(w, j + 2), w3 = __shfl(w, j + 3);
      int b0 = __shfl(b, j), b1 = __shfl(b, j + 1),
          b2 = __shfl(b, j + 2), b3 = __shfl(b, j + 3);
      unsigned v0 = *(const unsigned*)(xtb + b0 + lane * 4);
      unsigned v1 = *(const unsigned*)(xtb + b1 + lane * 4);
      unsigned v2 = *(const unsigned*)(xtb + b2 + lane * 4);
      unsigned v3 = *(const unsigned*)(xtb + b3 + lane * 4);
      acc0 += w0 * bflo(v0); acc1 += w0 * bfhi(v0);
      acc0 += w1 * bflo(v1); acc1 += w1 * bfhi(v1);
      acc0 += w2 * bflo(v2); acc1 += w2 * bfhi(v2);
      acc0 += w3 * bflo(v3); acc1 += w3 * bfhi(v3);
    }
    for (; j < cnt; ++j) {
      float w0 = __shfl(w, j);
      int b0 = __shfl(b, j);
      unsigned v0 = *(const unsigned*)(xtb + b0 + lane * 4);
      acc0 += w0 * bflo(v0); acc1 += w0 * bfhi(v0);
    }
  }
  float o0 = fmaxf(acc0 + bias[lane * 2], 0.f);
  float o1 = fmaxf(acc1 + bias[lane * 2 + 1], 0.f);
  union { float f[2]; unsigned long long u; } pk;
  pk.f[0] = o0; pk.f[1] = o1;
  __builtin_nontemporal_store(pk.u,
      (unsigned long long*)(out + (size_t)nl * 128 + lane * 2));
}

// -----------------------------------------------------------------------------
extern "C" void kernel_launch(void* const* d_in, const int* in_sizes, int n_in,
                              void* d_out, int out_size, void* d_ws, size_t ws_size,
                              hipStream_t stream) {
  const float* x1 = (const float*)d_in[0];
  const int* ei1 = (const int*)d_in[1];
  const int* et1 = (const int*)d_in[2];
  const float* x2 = (const float*)d_in[3];
  const int* ei2 = (const int*)d_in[4];
  const int* et2 = (const int*)d_in[5];
  const float* W1 = (const float*)d_in[6];
  const float* q1 = (const float*)d_in[7];
  const float* k1 = (const float*)d_in[8];
  const float* b1 = (const float*)d_in[9];
  const float* W2 = (const float*)d_in[10];
  const float* q2 = (const float*)d_in[11];
  const float* k2 = (const float*)d_in[12];
  const float* b2 = (const float*)d_in[13];

  const int N = in_sizes[0] / 128;
  const int E = in_sizes[1] / 2;
  const int R = in_sizes[6] / (128 * 128);
  const int KK = R * 4;
  const int N2 = 2 * N;
  const int NB = (N2 + 255) >> 8;           // 256-node buckets (<=512)

  size_t off = 0;
  char* w = (char*)d_ws;
  auto carve = [&](size_t bytes) -> void* {
    void* p = w + off;
    off += (bytes + 255) & ~(size_t)255;
    return p;
  };
  u16* xt = (u16*)carve((size_t)R * N * 128 * 2);       // per-graph, reused
  uint2* staged = (uint2*)xt;                           // ALIAS: dead before gemm_xt
  u16* Wb = (u16*)carve((size_t)2 * KK * 4096 * 2);
  u16* Bqk = (u16*)carve((size_t)2 * 4 * 64 * 8 * 2);
  float* Wq = (float*)carve((size_t)2 * R * 128 * 4);
  float* Wk = (float*)carve((size_t)2 * R * 128 * 4);
  float* sq = (float*)carve((size_t)N2 * 8 * 4);
  float* sk = (float*)carve((size_t)N2 * 8 * 4);
  int* offs = (int*)carve((size_t)(N2 + 1) * 4);
  int* gcnt = (int*)carve(512 * 4);
  int* bbase = (int*)carve(520 * 4);
  int* bcur = (int*)carve(512 * 4);
  int* csr = (int*)carve((size_t)2 * E * 4);
  if (off > ws_size) return;

  const int nbin = (2 * E + 4095) / 4096;

  hipMemsetAsync(gcnt, 0, 512 * 4, stream);
  k_prep_wb<<<dim3((KK * 512 + 255) / 256, 2), dim3(256), 0, stream>>>(W1, W2, Wb, KK);
  k_prep_wqk<<<dim3((2 * R * 128 * 64 + 255) / 256), dim3(256), 0, stream>>>(
      W1, q1, k1, W2, q2, k2, Wq, Wk, R * 128);
  k_prep_bqk<<<dim3(1), dim3(256), 0, stream>>>(Wq, Wk, Bqk, R);
  k_count<<<dim3(nbin), dim3(256), 0, stream>>>(ei1 + E, ei2 + E, gcnt, N, E, NB);
  k_bucket_scan<<<dim3(1), dim3(256), 0, stream>>>(gcnt, bbase, bcur, offs, NB, 2 * E, N2);
  k_bin<<<dim3(nbin), dim3(256), 0, stream>>>(ei1, et1, ei2, et2, bcur, staged, N, E, NB);
  k_scatter2<<<dim3(NB), dim3(256), 0, stream>>>(staged, bbase, offs, csr, N2);

  for (int g = 0; g < 2; ++g) {
    const float* x = g ? x2 : x1;
    const float* bv = g ? b2 : b1;
    float* outp = (float*)d_out + (size_t)g * N * 128;
    k_gemm_xt<<<dim3((N + 63) / 64), dim3(256), 0, stream>>>(
        x, Wb + (size_t)g * KK * 4096, Bqk + (size_t)g * 2048, xt,
        sq, sk, N, R, g * N);
    k_aggregate<<<dim3((N + 3) / 4), dim3(256), 0, stream>>>(
        csr, offs, sq, sk, xt, bv, outp, N, g * N);
  }
}

// Round 2
// 354.797 us; speedup vs baseline: 1.1379x; 1.1379x over previous
//
#include <hip/hip_runtime.h>

// RGATConv x2 (N=50000, E=800000, IN=HID=128, R=8) for MI355X/gfx950.
//
// Round-10: k_gemm_xt store path fixed. Keep operand swap (A=Wb/W^T,
// B=x fragments; [sq|sk] fused), but stage the accumulator through a
// WAVE-PRIVATE LDS buffer (8x ds_write_b64 per relation, no barriers) and
// store 1KB-contiguous global_store_dwordx4. Relations split across
// gridDim.y=2 (4 per block) to double occupancy. Round-9's direct uint2
// scatter store (16x 32B chunks/instr) was request-rate bound: 1.55 TB/s,
// 23% occupancy, 77us. Rest identical to round-9.

typedef unsigned short u16;
typedef __attribute__((ext_vector_type(8))) short short8;
typedef __attribute__((ext_vector_type(4))) float floatx4;
typedef __attribute__((ext_vector_type(4))) float float4v;
typedef __attribute__((ext_vector_type(4))) unsigned uint4v;

__device__ __forceinline__ u16 f2bf(float f) {
  union { float f; unsigned u; } v; v.f = f;
  unsigned r = v.u + 0x7FFFu + ((v.u >> 16) & 1u);  // RNE
  return (u16)(r >> 16);
}
__device__ __forceinline__ float bflo(unsigned v) {
  union { unsigned u; float f; } c; c.u = v << 16; return c.f;
}
__device__ __forceinline__ float bfhi(unsigned v) {
  union { unsigned u; float f; } c; c.u = v & 0xffff0000u; return c.f;
}

// ---- 1. pack stacked W into fragment order (per graph) ----------------------
// Layout: [(kkq*8 + nt)*64 + lane]*8 where element = W[k][c],
// c = nt*16 + (lane&15), k = kkq*32 + (lane>>4)*8 + j.
// Valid as B-fragment (col=c) AND as A-fragment of W^T (row=c).
__global__ void k_prep_wb(const float* __restrict__ W1, const float* __restrict__ W2,
                          u16* __restrict__ Wb, int KK) {
  int t = blockIdx.x * 256 + threadIdx.x;
  int lane = t & 63, nt = (t >> 6) & 7, kk = t >> 9;
  if (kk >= KK) return;
  const float* W = blockIdx.y ? W2 : W1;
  u16* out = Wb + (size_t)blockIdx.y * KK * 4096;
  int q = lane >> 4, m16 = lane & 15;
  int c = nt * 16 + m16;
  short8 v;
#pragma unroll
  for (int j = 0; j < 8; ++j) {
    int k = kk * 32 + q * 8 + j;
    v[j] = (short)f2bf(W[(size_t)k * 128 + c]);
  }
  *(short8*)(out + (size_t)t * 8) = v;
}

// ---- 2. Wq[g][r][d] = sum_c W[r][d][c]*q[c]; Wk likewise --------------------
__global__ void k_prep_wqk(const float* __restrict__ W1, const float* __restrict__ q1,
                           const float* __restrict__ k1, const float* __restrict__ W2,
                           const float* __restrict__ q2, const float* __restrict__ k2,
                           float* __restrict__ Wq, float* __restrict__ Wk, int RD) {
  int wid = (blockIdx.x * 256 + threadIdx.x) >> 6;
  int lane = threadIdx.x & 63;
  if (wid >= 2 * RD) return;
  int g = wid >= RD;
  const float* W = g ? W2 : W1;
  const float* qv = g ? q2 : q1;
  const float* kv = g ? k2 : k1;
  const float* row = W + (size_t)(wid - g * RD) * 128;
  float a0 = row[lane], a1 = row[lane + 64];
  float vq = a0 * qv[lane] + a1 * qv[lane + 64];
  float vk = a0 * kv[lane] + a1 * kv[lane + 64];
#pragma unroll
  for (int off = 32; off; off >>= 1) {
    vq += __shfl_xor(vq, off);
    vk += __shfl_xor(vk, off);
  }
  if (lane == 0) { Wq[wid] = vq; Wk[wid] = vk; }
}

// ---- 3. Bqk[g][kk][lane][j]: fragment of [Wq|Wk] (16 rows/cols) -------------
__global__ void k_prep_bqk(const float* __restrict__ Wq, const float* __restrict__ Wk,
                           u16* __restrict__ Bqk, int R) {
  int total = 2 * 4 * 64 * 8;
  for (int idx = threadIdx.x; idx < total; idx += 256) {
    int j = idx & 7, lane = (idx >> 3) & 63, kk = (idx >> 9) & 3, g = idx >> 11;
    int k = kk * 32 + ((lane >> 4) & 3) * 8 + j;
    int n = lane & 15;
    float v = (n < 8) ? Wq[(g * R + n) * 128 + k] : Wk[(g * R + (n & 7)) * 128 + k];
    Bqk[idx] = f2bf(v);
  }
}

// ---- 5a. bucket-level counts (LDS hist per block) ---------------------------
__global__ void __launch_bounds__(256) k_count(
    const int* __restrict__ d1, const int* __restrict__ d2,
    int* __restrict__ gcnt, int N, int E, int NB) {
  __shared__ int h[512];
  int tid = threadIdx.x;
  for (int i = tid; i < NB; i += 256) h[i] = 0;
  __syncthreads();
  int E2 = 2 * E;
  int e0 = blockIdx.x * 4096;
#pragma unroll
  for (int j = 0; j < 16; ++j) {
    int e = e0 + j * 256 + tid;
    if (e < E2) {
      int g = e >= E;
      int d = g ? d2[e - E] : d1[e];
      atomicAdd(&h[(g * N + d) >> 8], 1);
    }
  }
  __syncthreads();
  for (int i = tid; i < NB; i += 256)
    if (h[i]) atomicAdd(&gcnt[i], h[i]);
}

// ---- 5b. scan bucket totals -> bbase/bcur; offs[N2]=total -------------------
__global__ void k_bucket_scan(const int* __restrict__ gcnt, int* __restrict__ bbase,
                              int* __restrict__ bcur, int* __restrict__ offs,
                              int NB, int total, int N2) {
  __shared__ int sd[512];
  int tid = threadIdx.x;
  int v0 = (tid < NB) ? gcnt[tid] : 0;
  int v1 = (tid + 256 < NB) ? gcnt[tid + 256] : 0;
  sd[tid] = v0; sd[tid + 256] = v1;
  __syncthreads();
  for (int off = 1; off < 512; off <<= 1) {
    int t0 = (tid >= off) ? sd[tid - off] : 0;
    int t1 = (tid + 256 >= off) ? sd[tid + 256 - off] : 0;
    __syncthreads();
    sd[tid] += t0; sd[tid + 256] += t1;
    __syncthreads();
  }
  if (tid < NB) { int b = sd[tid] - v0; bbase[tid] = b; bcur[tid] = b; }
  if (tid + 256 < NB) { int b = sd[tid + 256] - v1; bbase[tid + 256] = b; bcur[tid + 256] = b; }
  if (tid == 0) { bbase[NB] = total; offs[N2] = total; }
}

// ---- 5c. bin edges into 256-node buckets (counting-sort per 4096-edge chunk)
__global__ void __launch_bounds__(256) k_bin(
    const int* __restrict__ ei1, const int* __restrict__ et1,
    const int* __restrict__ ei2, const int* __restrict__ et2,
    int* __restrict__ bcur, uint2* __restrict__ staged, int N, int E, int NB) {
  __shared__ int hist[512];
  __shared__ int basev[512];
  __shared__ int runstart[512];
  __shared__ unsigned sta[4096 * 2];  // 32 KB staging (dstg, srcet)
  int tid = threadIdx.x;
  int E2 = 2 * E;
  int e0 = blockIdx.x * 4096;
  int cnt2 = min(4096, E2 - e0);
  for (int i = tid; i < 512; i += 256) hist[i] = 0;
  __syncthreads();
  int dstg[16], srcet[16], rank[16];
#pragma unroll
  for (int j = 0; j < 16; ++j) {
    int e = e0 + j * 256 + tid;
    dstg[j] = -1;
    if (e < E2) {
      int g = e >= E;
      int el = e - (g ? E : 0);
      const int* ei = g ? ei2 : ei1;
      int s = ei[el], d = ei[E + el];
      int etv = (g ? et2 : et1)[el];
      dstg[j] = g * N + d;
      srcet[j] = (s << 3) | etv;
      rank[j] = atomicAdd(&hist[dstg[j] >> 8], 1);
    }
  }
  __syncthreads();
  basev[tid] = hist[tid];
  basev[tid + 256] = hist[tid + 256];
  __syncthreads();
  for (int off = 1; off < 512; off <<= 1) {
    int i0 = tid, i1 = tid + 256;
    int v0 = (i0 >= off) ? basev[i0 - off] : 0;
    int v1 = (i1 >= off) ? basev[i1 - off] : 0;
    __syncthreads();
    basev[i0] += v0; basev[i1] += v1;
    __syncthreads();
  }
  for (int i = tid; i < NB; i += 256)
    if (hist[i] > 0) runstart[i] = atomicAdd(&bcur[i], hist[i]);
  __syncthreads();
#pragma unroll
  for (int j = 0; j < 16; ++j)
    if (dstg[j] >= 0) {
      int b = dstg[j] >> 8;
      int slot = basev[b] - hist[b] + rank[j];
      sta[slot * 2] = (unsigned)dstg[j];
      sta[slot * 2 + 1] = (unsigned)srcet[j];
    }
  __syncthreads();
  for (int i = tid; i < cnt2; i += 256) {
    unsigned dg = sta[i * 2], se = sta[i * 2 + 1];
    int b = (int)(dg >> 8);
    int dest = runstart[b] + (i - (basev[b] - hist[b]));
    staged[dest] = make_uint2(dg, se);
  }
}

// ---- 5d. per-bucket: node-level offs + final sorted csr ---------------------
__global__ void __launch_bounds__(256) k_scatter2(
    const uint2* __restrict__ staged, const int* __restrict__ bbase,
    int* __restrict__ offs, int* __restrict__ csr, int N2) {
  __shared__ int hist[256];
  __shared__ int sd[256];
  __shared__ int cur[256];
  int b = blockIdx.x, tid = threadIdx.x;
  int nb0 = b << 8;
  int nnode = min(256, N2 - nb0);
  int s0 = bbase[b], s1 = bbase[b + 1];
  hist[tid] = 0;
  __syncthreads();
  for (int i = s0 + tid; i < s1; i += 256)
    atomicAdd(&hist[(int)staged[i].x - nb0], 1);
  __syncthreads();
  int v = hist[tid];
  sd[tid] = v; __syncthreads();
  for (int off = 1; off < 256; off <<= 1) {
    int t = (tid >= off) ? sd[tid - off] : 0;
    __syncthreads();
    sd[tid] += t;
    __syncthreads();
  }
  int ex = sd[tid] - v;  // exclusive scan
  if (tid < nnode) offs[nb0 + tid] = s0 + ex;
  cur[tid] = ex;
  __syncthreads();
  for (int i = s0 + tid; i < s1; i += 256) {
    uint2 en = staged[i];
    int node = (int)en.x - nb0;
    int sl = atomicAdd(&cur[node], 1);
    csr[s0 + sl] = (int)en.y;
  }
}

// ---- 6a. xt[r][n][c] = x_n @ W_r, fused [sq|sk] = x @ [Wq|Wk] ---------------
// A = Wb fragments (W^T: row index = out channel), B = x fragments (col =
// node). D[c][node]: lane holds col=node (lane&15), rows = channels
// nt*16 + q*4 + {0..3} (q = lane>>4). Accumulator goes through a
// WAVE-PRIVATE LDS tile (8x ds_write_b64, intra-wave DS ordering -> no
// barriers), then 4x {ds_read_b128 + global_store_dwordx4} emit 4KB of
// fully-contiguous xt rows. gridDim.y=2 splits relations (4 per block).
__global__ void __launch_bounds__(256) k_gemm_xt(
    const float* __restrict__ x, const u16* __restrict__ Wb,
    const u16* __restrict__ Bqk, u16* __restrict__ xt,
    float* __restrict__ sq, float* __restrict__ sk,
    int N, int R, int node_base) {
  __shared__ u16 st[4][16 * 136];
  int wave = threadIdx.x >> 6, lane = threadIdx.x & 63;
  int m0 = blockIdx.x * 64 + wave * 16;
  int rbase = blockIdx.y * 4;
  int q = lane >> 4, m16 = lane & 15;
  int node = m0 + m16;
  int srow = (node < N) ? node : N - 1;
  // B fragments of x: col = node, k = kk*32 + q*8 + j, loaded ONCE
  short8 bfrag[4];
#pragma unroll
  for (int kk = 0; kk < 4; ++kk) {
    const float* ap = x + (size_t)srow * 128 + kk * 32 + q * 8;
    float4v f0 = *(const float4v*)ap;
    float4v f1 = *(const float4v*)(ap + 4);
    short8 a;
    a[0] = (short)f2bf(f0.x); a[1] = (short)f2bf(f0.y);
    a[2] = (short)f2bf(f0.z); a[3] = (short)f2bf(f0.w);
    a[4] = (short)f2bf(f1.x); a[5] = (short)f2bf(f1.y);
    a[6] = (short)f2bf(f1.z); a[7] = (short)f2bf(f1.w);
    bfrag[kk] = a;
  }
  // fused [sq|sk] (only y==0 blocks): A = Bqk.
  // Lane q=0: sq[node][0..3], q=1: sq[node][4..7], q=2: sk[0..3], q=3: sk[4..7]
  if (blockIdx.y == 0) {
    floatx4 accq = (floatx4){0.f, 0.f, 0.f, 0.f};
#pragma unroll
    for (int kk = 0; kk < 4; ++kk) {
      short8 aq = *(const short8*)(Bqk + (size_t)kk * 512 + lane * 8);
      accq = __builtin_amdgcn_mfma_f32_16x16x32_bf16(aq, bfrag[kk], accq, 0, 0, 0);
    }
    if (node < N) {
      float* dst = (q < 2 ? sq : sk) + (size_t)(node_base + node) * 8 + (q & 1) * 4;
      *(float4v*)dst = (float4v){accq[0], accq[1], accq[2], accq[3]};
    }
  }
  u16* s = st[wave];
  for (int rr = 0; rr < 4; ++rr) {
    int r = rbase + rr;
    floatx4 acc[8];
#pragma unroll
    for (int nt = 0; nt < 8; ++nt) acc[nt] = (floatx4){0.f, 0.f, 0.f, 0.f};
#pragma unroll
    for (int kk = 0; kk < 4; ++kk) {
      const u16* wbp = Wb + ((size_t)((r * 4 + kk) * 8) * 64 + lane) * 8;
#pragma unroll
      for (int nt = 0; nt < 8; ++nt) {
        short8 a = *(const short8*)(wbp + nt * 512);
        acc[nt] = __builtin_amdgcn_mfma_f32_16x16x32_bf16(a, bfrag[kk], acc[nt], 0, 0, 0);
      }
    }
    // transpose via wave-private LDS: row = m16 (local node), 4 consecutive
    // channels per lane per nt -> 8B ds_write_b64
#pragma unroll
    for (int nt = 0; nt < 8; ++nt) {
      union { u16 h[4]; unsigned long long u; } pk;
      pk.h[0] = f2bf(acc[nt][0]); pk.h[1] = f2bf(acc[nt][1]);
      pk.h[2] = f2bf(acc[nt][2]); pk.h[3] = f2bf(acc[nt][3]);
      *(unsigned long long*)(s + m16 * 136 + nt * 16 + q * 4) = pk.u;
    }
    // read back row-major, 1KB contiguous per instruction (4 rows x 256B)
#pragma unroll
    for (int it = 0; it < 4; ++it) {
      int m = it * 4 + q;
      int gm = m0 + m;
      if (gm < N) {
        uint4v vv = *(const uint4v*)(s + m * 136 + m16 * 8);
        *(uint4v*)(xt + ((size_t)r * N + gm) * 128 + m16 * 8) = vv;
      }
    }
  }
}

// ---- 6b. per-dst softmax + gather: one wave per node ------------------------
__global__ void __launch_bounds__(256) k_aggregate(
    const int* __restrict__ csr, const int* __restrict__ offs,
    const float* __restrict__ sq, const float* __restrict__ sk,
    const u16* __restrict__ xt, const float* __restrict__ bias,
    float* __restrict__ out, int N, int node_base) {
  int nl = blockIdx.x * 4 + (threadIdx.x >> 6);
  int lane = threadIdx.x & 63;
  if (nl >= N) return;
  int node = node_base + nl;
  int start = offs[node], end = offs[node + 1];
  const float* sqn = sq + (size_t)node * 8;

  float al[8]; int pl[8];
  float m = -INFINITY;
  {
    int c = 0;
    for (int i = start + lane; i < end; i += 64, ++c) {
      int p = csr[i]; int s = p >> 3, e = p & 7;
      float a = sqn[e] + sk[(size_t)(node_base + s) * 8 + e];
      a = (a > 0.f) ? a : 0.2f * a;
      if (c < 8) { al[c] = a; pl[c] = p; }
      m = fmaxf(m, a);
    }
  }
#pragma unroll
  for (int off = 32; off; off >>= 1) m = fmaxf(m, __shfl_xor(m, off));

  float ssum = 0.f;
  {
    int c = 0;
    for (int i = start + lane; i < end; i += 64, ++c) {
      float a;
      if (c < 8) a = al[c];
      else {
        int p = csr[i]; int s = p >> 3, e = p & 7;
        a = sqn[e] + sk[(size_t)(node_base + s) * 8 + e];
        a = (a > 0.f) ? a : 0.2f * a;
      }
      ssum += __expf(a - m);
    }
  }
#pragma unroll
  for (int off = 32; off; off >>= 1) ssum += __shfl_xor(ssum, off);
  float inv = 1.f / (ssum + 1e-16f);

  float acc0 = 0.f, acc1 = 0.f;
  const char* xtb = (const char*)xt;
  int c = 0;
  for (int base = start; base < end; base += 64, ++c) {
    int cnt = min(64, end - base);
    float w = 0.f; int b = 0;
    {
      int i = base + lane;
      if (i < end) {
        int p; float a;
        if (c < 8) { p = pl[c]; a = al[c]; }
        else {
          p = csr[i]; int s = p >> 3, e = p & 7;
          a = sqn[e] + sk[(size_t)(node_base + s) * 8 + e];
          a = (a > 0.f) ? a : 0.2f * a;
        }
        w = __expf(a - m) * inv;
        b = ((p & 7) * N + (p >> 3)) << 8;  // xt row base in BYTES
      }
    }
    int j = 0;
    for (; j + 3 < cnt; j += 4) {
      float w0 = __shfl(w, j), w1 = __shfl(w, j + 1),
            w2 = __shfl(w, j + 2), w3 = __shfl(w, j + 3);
      int b0 = __shfl(b, j), b1 = __shfl(b, j + 1),
          b2 = __shfl(b, j + 2), b3 = __shfl(b, j + 3);
      unsigned v0 = *(const unsigned*)(xtb + b0 + lane * 4);
      unsigned v1 = *(const unsigned*)(xtb + b1 + lane * 4);
      unsigned v2 = *(const unsigned*)(xtb + b2 + lane * 4);
      unsigned v3 = *(const unsigned*)(xtb + b3 + lane * 4);
      acc0 += w0 * bflo(v0); acc1 += w0 * bfhi(v0);
      acc0 += w1 * bflo(v1); acc1 += w1 * bfhi(v1);
      acc0 += w2 * bflo(v2); acc1 += w2 * bfhi(v2);
      acc0 += w3 * bflo(v3); acc1 += w3 * bfhi(v3);
    }
    for (; j < cnt; ++j) {
      float w0 = __shfl(w, j);
      int b0 = __shfl(b, j);
      unsigned v0 = *(const unsigned*)(xtb + b0 + lane * 4);
      acc0 += w0 * bflo(v0); acc1 += w0 * bfhi(v0);
    }
  }
  float o0 = fmaxf(acc0 + bias[lane * 2], 0.f);
  float o1 = fmaxf(acc1 + bias[lane * 2 + 1], 0.f);
  union { float f[2]; unsigned long long u; } pk;
  pk.f[0] = o0; pk.f[1] = o1;
  __builtin_nontemporal_store(pk.u,
      (unsigned long long*)(out + (size_t)nl * 128 + lane * 2));
}

// -----------------------------------------------------------------------------
extern "C" void kernel_launch(void* const* d_in, const int* in_sizes, int n_in,
                              void* d_out, int out_size, void* d_ws, size_t ws_size,
                              hipStream_t stream) {
  const float* x1 = (const float*)d_in[0];
  const int* ei1 = (const int*)d_in[1];
  const int* et1 = (const int*)d_in[2];
  const float* x2 = (const float*)d_in[3];
  const int* ei2 = (const int*)d_in[4];
  const int* et2 = (const int*)d_in[5];
  const float* W1 = (const float*)d_in[6];
  const float* q1 = (const float*)d_in[7];
  const float* k1 = (const float*)d_in[8];
  const float* b1 = (const float*)d_in[9];
  const float* W2 = (const float*)d_in[10];
  const float* q2 = (const float*)d_in[11];
  const float* k2 = (const float*)d_in[12];
  const float* b2 = (const float*)d_in[13];

  const int N = in_sizes[0] / 128;
  const int E = in_sizes[1] / 2;
  const int R = in_sizes[6] / (128 * 128);
  const int KK = R * 4;
  const int N2 = 2 * N;
  const int NB = (N2 + 255) >> 8;           // 256-node buckets (<=512)

  size_t off = 0;
  char* w = (char*)d_ws;
  auto carve = [&](size_t bytes) -> void* {
    void* p = w + off;
    off += (bytes + 255) & ~(size_t)255;
    return p;
  };
  u16* xt = (u16*)carve((size_t)R * N * 128 * 2);       // per-graph, reused
  uint2* staged = (uint2*)xt;                           // ALIAS: dead before gemm_xt
  u16* Wb = (u16*)carve((size_t)2 * KK * 4096 * 2);
  u16* Bqk = (u16*)carve((size_t)2 * 4 * 64 * 8 * 2);
  float* Wq = (float*)carve((size_t)2 * R * 128 * 4);
  float* Wk = (float*)carve((size_t)2 * R * 128 * 4);
  float* sq = (float*)carve((size_t)N2 * 8 * 4);
  float* sk = (float*)carve((size_t)N2 * 8 * 4);
  int* offs = (int*)carve((size_t)(N2 + 1) * 4);
  int* gcnt = (int*)carve(512 * 4);
  int* bbase = (int*)carve(520 * 4);
  int* bcur = (int*)carve(512 * 4);
  int* csr = (int*)carve((size_t)2 * E * 4);
  if (off > ws_size) return;

  const int nbin = (2 * E + 4095) / 4096;

  hipMemsetAsync(gcnt, 0, 512 * 4, stream);
  k_prep_wb<<<dim3((KK * 512 + 255) / 256, 2), dim3(256), 0, stream>>>(W1, W2, Wb, KK);
  k_prep_wqk<<<dim3((2 * R * 128 * 64 + 255) / 256), dim3(256), 0, stream>>>(
      W1, q1, k1, W2, q2, k2, Wq, Wk, R * 128);
  k_prep_bqk<<<dim3(1), dim3(256), 0, stream>>>(Wq, Wk, Bqk, R);
  k_count<<<dim3(nbin), dim3(256), 0, stream>>>(ei1 + E, ei2 + E, gcnt, N, E, NB);
  k_bucket_scan<<<dim3(1), dim3(256), 0, stream>>>(gcnt, bbase, bcur, offs, NB, 2 * E, N2);
  k_bin<<<dim3(nbin), dim3(256), 0, stream>>>(ei1, et1, ei2, et2, bcur, staged, N, E, NB);
  k_scatter2<<<dim3(NB), dim3(256), 0, stream>>>(staged, bbase, offs, csr, N2);

  for (int g = 0; g < 2; ++g) {
    const float* x = g ? x2 : x1;
    const float* bv = g ? b2 : b1;
    float* outp = (float*)d_out + (size_t)g * N * 128;
    k_gemm_xt<<<dim3((N + 63) / 64, 2), dim3(256), 0, stream>>>(
        x, Wb + (size_t)g * KK * 4096, Bqk + (size_t)g * 2048, xt,
        sq, sk, N, R, g * N);
    k_aggregate<<<dim3((N + 3) / 4), dim3(256), 0, stream>>>(
        csr, offs, sq, sk, xt, bv, outp, N, g * N);
  }
}